// Round 2
// baseline (142.712 us; speedup 1.0000x reference)
//
#include <hip/hip_runtime.h>

typedef _Float16 f16x8  __attribute__((ext_vector_type(8)));
typedef __fp16   h16x2  __attribute__((ext_vector_type(2)));
typedef float    f32x16 __attribute__((ext_vector_type(16)));

#define NLAYER 5
#define NTILES 8192          // 1048576 / 128 rows per block-pass
#define GRID   2048          // each block loops 4 tiles

static __device__ __forceinline__ int pkrtz(float a, float b) {
    h16x2 p = __builtin_amdgcn_cvt_pkrtz(a, b);
    return __builtin_bit_cast(int, p);
}

// ---------------------------------------------------------------------------
// Prep: convert f32 weights -> fp16, laid out in exact MFMA A-fragment order:
//   half index = ((((L*2+t)*4+f)*64)+lane)*8 + e
//   value      = W[L][w = 32t + (lane&31)][k = 8*(lane>>5) + 16f + e]
// so the main kernel's per-lane fragment load is a single contiguous 16B read.
// ---------------------------------------------------------------------------
__global__ __launch_bounds__(256) void prep_weights(
    const float* __restrict__ w_in, const float* __restrict__ w_hid,
    const float* __restrict__ w_out, _Float16* __restrict__ wf)
{
    int idx = blockIdx.x * 256 + threadIdx.x;      // exactly 20480 threads
    int e = idx & 7;
    int l = (idx >> 3) & 63;
    int f = (idx >> 9) & 3;
    int t = (idx >> 11) & 1;
    int L = idx >> 12;
    int w = t * 32 + (l & 31);
    int k = ((l >> 5) << 3) + (f << 4) + e;
    float v;
    if (L == 0)       v = w_in[w * 64 + k];
    else if (L <= 3)  v = w_hid[((L - 1) * 64 + w) * 64 + k];
    else              v = w_out[w * 64 + k];
    wf[idx] = (_Float16)v;
}

// ---------------------------------------------------------------------------
// Fused MLP. Per wave: 32 batch rows, all 5 layers in registers.
//  - B-fragment (activations): col b = lane&31 (invariant!), k = 8*(lane>>5)+e
//  - A-fragment (weights):     row w = lane&31, k = 8*(lane>>5)+e  (from LDS)
//  - C/D layout (verified m74/m101): col = lane&31,
//      row = (reg&3) + 8*(reg>>2) + 4*(lane>>5)
//  Inter-layer: relu(f32) -> cvt_pkrtz pairs -> half-wave exchange via
//  ds_bpermute(lane^32) + lane<32 select rebuilds the next B-fragments.
// ---------------------------------------------------------------------------
__global__ __launch_bounds__(256) void mlp_kernel(
    const float* __restrict__ x, const f16x8* __restrict__ wfrag_g,
    float* __restrict__ out)
{
    __shared__ f16x8 Wlds[NLAYER * 8 * 64];        // 40960 B

    const int tid = threadIdx.x;
    {   // linear 40 KB fill, coalesced float4, frag order already correct
        const float4* src = (const float4*)wfrag_g;
        float4*       dst = (float4*)Wlds;
#pragma unroll
        for (int i = 0; i < 10; ++i) dst[tid + i * 256] = src[tid + i * 256];
    }
    __syncthreads();

    const int  lane   = tid & 63;
    const int  wid    = tid >> 6;
    const int  g      = lane >> 5;      // 0/1 : k-half
    const int  bl     = lane & 31;      // batch column within tile
    const bool lo     = lane < 32;
    const int  swaddr = (lane ^ 32) << 2;

    for (int T = blockIdx.x; T < NTILES; T += gridDim.x) {
        const int row = T * 128 + wid * 32 + bl;

        // ---- load X tile rows, build layer-0 B-fragments -------------------
        const float4* xp = (const float4*)(x + (size_t)row * 64) + 2 * g;
        float4 xa[4], xb[4];
#pragma unroll
        for (int F = 0; F < 4; ++F) { xa[F] = xp[4 * F]; xb[F] = xp[4 * F + 1]; }

        f16x8 h[4];
#pragma unroll
        for (int F = 0; F < 4; ++F) {
            int4 packed = make_int4(pkrtz(xa[F].x, xa[F].y),
                                    pkrtz(xa[F].z, xa[F].w),
                                    pkrtz(xb[F].x, xb[F].y),
                                    pkrtz(xb[F].z, xb[F].w));
            h[F] = __builtin_bit_cast(f16x8, packed);
        }

        // ---- 5 layers ------------------------------------------------------
#pragma unroll
        for (int L = 0; L < NLAYER; ++L) {
            f32x16 acc0, acc1;
#pragma unroll
            for (int i = 0; i < 16; ++i) { acc0[i] = 0.0f; acc1[i] = 0.0f; }

            const f16x8* WL = &Wlds[L * 8 * 64];
#pragma unroll
            for (int f = 0; f < 4; ++f) {
                acc0 = __builtin_amdgcn_mfma_f32_32x32x16_f16(
                           WL[f * 64 + lane],       h[f], acc0, 0, 0, 0);
                acc1 = __builtin_amdgcn_mfma_f32_32x32x16_f16(
                           WL[(4 + f) * 64 + lane], h[f], acc1, 0, 0, 0);
            }

            if (L < NLAYER - 1) {
                // relu (f32) + pack to fp16 pairs: c[t][j] covers
                //   w = 32t + 4g + 8*(j>>1) + 2*(j&1) + {0,1}
                int c[2][8];
#pragma unroll
                for (int j = 0; j < 8; ++j) {
                    c[0][j] = pkrtz(fmaxf(acc0[2 * j], 0.0f),
                                    fmaxf(acc0[2 * j + 1], 0.0f));
                    c[1][j] = pkrtz(fmaxf(acc1[2 * j], 0.0f),
                                    fmaxf(acc1[2 * j + 1], 0.0f));
                }
                // rebuild next-layer B-fragments: frag F dword d holds
                //   k = 16F + 8g + 2d .. +1   (half-wave exchange)
#pragma unroll
                for (int F = 0; F < 4; ++F) {
                    const int t = F >> 1;
                    int dw[4];
#pragma unroll
                    for (int p = 0; p < 2; ++p) {
                        const int j0 = ((2 * F) & 3) * 2 + p;
                        const int j1 = ((2 * F + 1) & 3) * 2 + p;
                        int xv  = c[t][j0];
                        int yv  = c[t][j1];
                        int xsw = __builtin_amdgcn_ds_bpermute(swaddr, xv);
                        int ysw = __builtin_amdgcn_ds_bpermute(swaddr, yv);
                        dw[p]     = lo ? xv  : ysw;   // k-dword d = p
                        dw[p + 2] = lo ? xsw : yv;    // k-dword d = p+2
                    }
                    int4 packed = make_int4(dw[0], dw[1], dw[2], dw[3]);
                    h[F] = __builtin_bit_cast(f16x8, packed);
                }
            } else {
                // ---- store f32 output: reg r -> col (r&3)+8*(r>>2)+4g+32t --
                float* orow = out + (size_t)row * 64 + g * 4;
#pragma unroll
                for (int q = 0; q < 4; ++q) {
                    float4 v0 = make_float4(acc0[4 * q], acc0[4 * q + 1],
                                            acc0[4 * q + 2], acc0[4 * q + 3]);
                    *(float4*)(orow + q * 8) = v0;
                    float4 v1 = make_float4(acc1[4 * q], acc1[4 * q + 1],
                                            acc1[4 * q + 2], acc1[4 * q + 3]);
                    *(float4*)(orow + 32 + q * 8) = v1;
                }
            }
        }
    }
}

extern "C" void kernel_launch(void* const* d_in, const int* in_sizes, int n_in,
                              void* d_out, int out_size, void* d_ws, size_t ws_size,
                              hipStream_t stream)
{
    const float* x    = (const float*)d_in[0];
    const float* w_in = (const float*)d_in[1];
    const float* w_h  = (const float*)d_in[2];
    const float* w_o  = (const float*)d_in[3];

    _Float16* wf = (_Float16*)d_ws;                 // 20480 halves = 40 KB
    prep_weights<<<80, 256, 0, stream>>>(w_in, w_h, w_o, wf);
    mlp_kernel<<<GRID, 256, 0, stream>>>(x, (const f16x8*)d_ws, (float*)d_out);
}